// Round 3
// baseline (1172.497 us; speedup 1.0000x reference)
//
#include <hip/hip_runtime.h>
#include <math.h>

// Problem dims (fixed by the reference setup_inputs)
constexpr int B = 8, C = 7, T = 45;
constexpr int S = 4096, D = 5120;

constexpr int NCHUNK = 16;            // S split for parallelism
constexpr int SCHUNK = S / NCHUNK;    // 256 rows per chunk
constexpr int D4 = D / 4;             // 1280 float4 columns
constexpr int BLK = 256;
constexpr int D4_BLOCKS = D4 / BLK;   // 5

// ---------------------------------------------------------------------------
// Kernel 1: per-(b,c) min-max normalize over T. One 64-thread wave per row.
__global__ void xnorm_kernel(const float* __restrict__ x, float* __restrict__ out_xn) {
    int row = blockIdx.x;      // 0 .. B*C-1
    int lane = threadIdx.x;    // 0 .. 63
    const float* xr = x + row * T;
    float v  = (lane < T) ? xr[lane] : 0.0f;
    float mn = (lane < T) ? v : INFINITY;
    float mx = (lane < T) ? v : -INFINITY;
    #pragma unroll
    for (int off = 32; off > 0; off >>= 1) {
        mn = fminf(mn, __shfl_xor(mn, off, 64));
        mx = fmaxf(mx, __shfl_xor(mx, off, 64));
    }
    if (lane < T) {
        float y = (mx > mn) ? (v - mn) / (mx - mn) : v;
        out_xn[row * T + lane] = y;
    }
}

// ---------------------------------------------------------------------------
// Kernel 2: series_mean[b][t] = mean over C of x[b][c][t]  -> workspace
__global__ void smean_kernel(const float* __restrict__ x, float* __restrict__ sm) {
    int b = blockIdx.x;
    int t = threadIdx.x;
    if (t < T) {
        float s = 0.0f;
        #pragma unroll
        for (int c = 0; c < C; ++c) s += x[(b * C + c) * T + t];
        sm[b * T + t] = s * (1.0f / C);
    }
}

// ---------------------------------------------------------------------------
// Kernel 3: series_emb = sm @ W + b, L2-normalized; writes e_fused BASE into out.
// One block per batch row. Each thread owns D/BLK = 20 output columns.
__global__ __launch_bounds__(BLK) void semb_kernel(const float* __restrict__ sm,
                                                   const float* __restrict__ W,
                                                   const float* __restrict__ bias,
                                                   float* __restrict__ out) {
    int b = blockIdx.x;
    int tid = threadIdx.x;
    __shared__ float s_sm[T];
    __shared__ float red[BLK / 64];
    if (tid < T) s_sm[tid] = sm[b * T + tid];
    __syncthreads();

    float vals[D / BLK];   // 20 values
    float ss = 0.0f;
    #pragma unroll
    for (int k = 0; k < D / BLK; ++k) {
        int d = tid + k * BLK;
        float v = bias[d];
        #pragma unroll
        for (int t = 0; t < T; ++t) v = fmaf(s_sm[t], W[t * D + d], v);
        vals[k] = v;
        ss = fmaf(v, v, ss);
    }
    // block-wide sum of squares
    #pragma unroll
    for (int off = 32; off > 0; off >>= 1) ss += __shfl_xor(ss, off, 64);
    if ((tid & 63) == 0) red[tid >> 6] = ss;
    __syncthreads();
    float tot = red[0] + red[1] + red[2] + red[3];
    float inv = 1.0f / fmaxf(sqrtf(tot), 1e-12f);
    #pragma unroll
    for (int k = 0; k < D / BLK; ++k) {
        out[b * D + tid + k * BLK] = vals[k] * inv;
    }
}

// ---------------------------------------------------------------------------
// Kernel 4: e_text accumulation. The only HBM-heavy kernel: streams 671 MB.
// Thread <-> one float4 column of one S-chunk; coalesced 1 KiB/wave reads.
__global__ __launch_bounds__(BLK) void etext_kernel(const float* __restrict__ hs,
                                                    float* __restrict__ out) {
    int blk   = blockIdx.x;             // 0 .. B*NCHUNK*D4_BLOCKS-1
    int d4blk = blk % D4_BLOCKS;
    int tmp   = blk / D4_BLOCKS;
    int chunk = tmp % NCHUNK;
    int b     = tmp / NCHUNK;
    int d4    = d4blk * BLK + threadIdx.x;   // 0 .. 1279

    const float4* p = reinterpret_cast<const float4*>(
                          hs + (size_t)b * S * D + (size_t)chunk * SCHUNK * D) + d4;
    float4 acc = make_float4(0.f, 0.f, 0.f, 0.f);
    #pragma unroll 8
    for (int s = 0; s < SCHUNK; ++s) {
        float4 v = p[(size_t)s * D4];
        acc.x += v.x; acc.y += v.y; acc.z += v.z; acc.w += v.w;
    }
    constexpr float scale = 1.0f / S;
    float* o = out + (size_t)b * D + (size_t)d4 * 4;
    atomicAdd(o + 0, acc.x * scale);
    atomicAdd(o + 1, acc.y * scale);
    atomicAdd(o + 2, acc.z * scale);
    atomicAdd(o + 3, acc.w * scale);
}

// ---------------------------------------------------------------------------
extern "C" void kernel_launch(void* const* d_in, const int* in_sizes, int n_in,
                              void* d_out, int out_size, void* d_ws, size_t ws_size,
                              hipStream_t stream) {
    const float* x    = (const float*)d_in[0];   // [B,C,T]
    const float* hs   = (const float*)d_in[1];   // [B,S,D]
    const float* W    = (const float*)d_in[2];   // [T,D]
    const float* bias = (const float*)d_in[3];   // [D]
    float* out = (float*)d_out;                  // e_fused [B,D] then x_norm [B,C,T]
    float* sm  = (float*)d_ws;                   // series_mean [B,T]

    // x_normalized -> second output region
    xnorm_kernel<<<B * C, 64, 0, stream>>>(x, out + B * D);
    // series_mean -> ws
    smean_kernel<<<B, 64, 0, stream>>>(x, sm);
    // normalized series_emb -> e_fused base (also overwrites the 0xAA poison)
    semb_kernel<<<B, BLK, 0, stream>>>(sm, W, bias, out);
    // e_text accumulated on top (same stream => ordered after semb)
    etext_kernel<<<B * NCHUNK * D4_BLOCKS, BLK, 0, stream>>>(hs, out);
}